// Round 6
// baseline (68.262 us; speedup 1.0000x reference)
//
#include <hip/hip_runtime.h>
#include <math.h>

#define IOTA_F (1.0f / 137.0f)
#define PHI_F  0.618033988749894f

__device__ __forceinline__ float sigm(float x) { return 1.0f / (1.0f + expf(-x)); }

__device__ __forceinline__ float nan2num(float v) {
    if (isnan(v)) return IOTA_F;
    if (isinf(v)) return v > 0.0f ? 1.0f : IOTA_F;
    return v;
}

// ---------------------------------------------------------------------------
// Kernel 1: instance_norm(5) -> rfft(5) -> re*im -> sigmoid -> softmax(3)
//           -> bilinear(3x3 -> 9) -> mask(u1) -> B1[9][2048]
// ---------------------------------------------------------------------------
__global__ void k_pre(const float* __restrict__ signal,  // [5][2048]
                      const float* __restrict__ u1,      // [9][2048]
                      const float* __restrict__ bilW,    // [9][3][3]
                      const float* __restrict__ bilb,    // [9]
                      float* __restrict__ B1)            // [9][2048]
{
    int s = blockIdx.x * blockDim.x + threadIdx.x;
    if (s >= 2048) return;

    float x0 = signal[0 * 2048 + s];
    float x1 = signal[1 * 2048 + s];
    float x2 = signal[2 * 2048 + s];
    float x3 = signal[3 * 2048 + s];
    float x4 = signal[4 * 2048 + s];

    float mean = (x0 + x1 + x2 + x3 + x4) * 0.2f;
    float d0 = x0 - mean, d1 = x1 - mean, d2 = x2 - mean, d3 = x3 - mean, d4 = x4 - mean;
    float var = (d0 * d0 + d1 * d1 + d2 * d2 + d3 * d3 + d4 * d4) * 0.2f;
    float r = 1.0f / sqrtf(var + 1e-9f);
    d0 *= r; d1 *= r; d2 *= r; d3 *= r; d4 *= r;

    const float c1 = 0.30901699437494742f;   // cos(2pi/5)
    const float c2 = -0.80901699437494745f;  // cos(4pi/5)
    const float s1 = 0.95105651629515357f;   // sin(2pi/5)
    const float s2 = 0.58778525229247314f;   // sin(4pi/5)

    float re1 = d0 + c1 * (d1 + d4) + c2 * (d2 + d3);
    float im1 = -(s1 * (d1 - d4) + s2 * (d2 - d3));
    float re2 = d0 + c2 * (d1 + d4) + c1 * (d2 + d3);
    float im2 = -s2 * (d1 - d4) + s1 * (d2 - d3);

    float p1 = nan2num(re1 * im1);
    float p2 = nan2num(re2 * im2);
    float g0 = 0.5f;                 // k=0: imag == 0 -> sigmoid(0) = 0.5
    float g1 = sigm(p1);
    float g2 = sigm(p2);

    float mx = fmaxf(g0, fmaxf(g1, g2));
    float e0 = expf(g0 - mx), e1 = expf(g1 - mx), e2 = expf(g2 - mx);
    float inv = 1.0f / (e0 + e1 + e2);
    float w[3] = { e0 * inv, e1 * inv, e2 * inv };

    #pragma unroll
    for (int kk = 0; kk < 9; ++kk) {
        float acc = bilb[kk];
        #pragma unroll
        for (int i = 0; i < 3; ++i)
            #pragma unroll
            for (int j = 0; j < 3; ++j)
                acc += w[i] * bilW[kk * 9 + i * 3 + j] * w[j];
        float mask = (u1[kk * 2048 + s] < PHI_F) ? 1.0f : 0.0f;
        B1[kk * 2048 + s] = IOTA_F + acc * mask;
    }
}

// ---------------------------------------------------------------------------
// Kernel 2: fused LSTM layer (gemv + nonlinearity) — round-4 structure,
// unroll deepened 2 -> 4.
// Block = 256 threads = 4 waves; block covers 4 q-columns (grid 512 = 2/CU).
//   wave w owns K-chunk w (512 floats); group g (16 lanes) owns q = q0+g and
//   its THREE live gate rows {q, 4096+q, 6144+q} (i,g,o; f dead since c0=0).
//   After shfl+LDS reduce, epilogue computes
//     h = sigmoid(o) * tanh(sigmoid(i) * tanh(g))  (+ optional u-mask)
//   and writes Bout[m][q] directly.
// ---------------------------------------------------------------------------
template <bool MASK>
__global__ __launch_bounds__(256, 2) void k_lstm_fused(
    const float* __restrict__ Bv,   // [9][2048]
    const float* __restrict__ W,    // [8192][2048]
    const float* __restrict__ b1,   // [8192]
    const float* __restrict__ b2,   // [8192]
    const float* __restrict__ u,    // [9][2048] or null
    float* __restrict__ Bout)       // [9][2048]
{
    __shared__ float lds[4][4][3][9];

    const int tid  = threadIdx.x;
    const int w    = tid >> 6;      // wave = K-chunk
    const int lane = tid & 63;
    const int grp  = lane >> 4;     // q within block
    const int li   = lane & 15;

    const int q = blockIdx.x * 4 + grp;

    const float4* __restrict__ B4 = reinterpret_cast<const float4*>(Bv);
    const float4* __restrict__ Wi = reinterpret_cast<const float4*>(W) + (size_t)q * 512;
    const float4* __restrict__ Wg = Wi + (size_t)4096 * 512;
    const float4* __restrict__ Wo = Wi + (size_t)6144 * 512;

    float acc[3][9];
    #pragma unroll
    for (int r = 0; r < 3; ++r)
        #pragma unroll
        for (int m = 0; m < 9; ++m) acc[r][m] = 0.0f;

    const int kb4 = w * 128;

    #pragma unroll 4
    for (int it = 0; it < 8; ++it) {
        const int idx = kb4 + it * 16 + li;
        float4 bv[9];
        #pragma unroll
        for (int m = 0; m < 9; ++m) bv[m] = B4[m * 512 + idx];
        float4 wv0 = Wi[idx];
        float4 wv1 = Wg[idx];
        float4 wv2 = Wo[idx];
        #pragma unroll
        for (int m = 0; m < 9; ++m) {
            acc[0][m] = fmaf(wv0.x, bv[m].x, acc[0][m]);
            acc[0][m] = fmaf(wv0.y, bv[m].y, acc[0][m]);
            acc[0][m] = fmaf(wv0.z, bv[m].z, acc[0][m]);
            acc[0][m] = fmaf(wv0.w, bv[m].w, acc[0][m]);
            acc[1][m] = fmaf(wv1.x, bv[m].x, acc[1][m]);
            acc[1][m] = fmaf(wv1.y, bv[m].y, acc[1][m]);
            acc[1][m] = fmaf(wv1.z, bv[m].z, acc[1][m]);
            acc[1][m] = fmaf(wv1.w, bv[m].w, acc[1][m]);
            acc[2][m] = fmaf(wv2.x, bv[m].x, acc[2][m]);
            acc[2][m] = fmaf(wv2.y, bv[m].y, acc[2][m]);
            acc[2][m] = fmaf(wv2.z, bv[m].z, acc[2][m]);
            acc[2][m] = fmaf(wv2.w, bv[m].w, acc[2][m]);
        }
    }

    #pragma unroll
    for (int r = 0; r < 3; ++r)
        #pragma unroll
        for (int m = 0; m < 9; ++m) {
            float v = acc[r][m];
            v += __shfl_xor(v, 1);
            v += __shfl_xor(v, 2);
            v += __shfl_xor(v, 4);
            v += __shfl_xor(v, 8);
            acc[r][m] = v;
        }

    if (li == 0) {
        #pragma unroll
        for (int r = 0; r < 3; ++r)
            #pragma unroll
            for (int m = 0; m < 9; ++m)
                lds[w][grp][r][m] = acc[r][m];
    }
    __syncthreads();

    if (tid < 36) {
        const int qq = tid / 9;
        const int m  = tid - qq * 9;
        const int qg = blockIdx.x * 4 + qq;
        float iv = lds[0][qq][0][m] + lds[1][qq][0][m] + lds[2][qq][0][m] + lds[3][qq][0][m];
        float gv = lds[0][qq][1][m] + lds[1][qq][1][m] + lds[2][qq][1][m] + lds[3][qq][1][m];
        float ov = lds[0][qq][2][m] + lds[1][qq][2][m] + lds[2][qq][2][m] + lds[3][qq][2][m];
        iv += b1[qg] + b2[qg];
        gv += b1[4096 + qg] + b2[4096 + qg];
        ov += b1[6144 + qg] + b2[6144 + qg];
        float c = sigm(iv) * tanhf(gv);
        float h = sigm(ov) * tanhf(c);
        if (MASK) h = IOTA_F + h * ((u[m * 2048 + qg] < PHI_F) ? 1.0f : 0.0f);
        Bout[m * 2048 + qg] = h;
    }
}

// ---------------------------------------------------------------------------
// Kernel 3: linear gemv — round-4 structure, unroll 2 -> 4.
// Block = 4 waves, 4*R rows (grid 512 = 2/CU, R=5).
//   wave w = K-chunk; group g handles rows row0+g*R .. +R-1 with
//   register-cached B. LDS cross-wave reduce; bias added; writes Z.
// ---------------------------------------------------------------------------
template <int R>
__global__ __launch_bounds__(256, 2) void k_gemvR(
    const float* __restrict__ Bv,    // [9][2048]
    const float* __restrict__ W,     // [nrows][2048]
    const float* __restrict__ bias,  // [nrows]
    float* __restrict__ Out,         // [9][nrows]
    int nrows)
{
    __shared__ float lds[4][4 * R][9];

    const int tid  = threadIdx.x;
    const int w    = tid >> 6;
    const int lane = tid & 63;
    const int grp  = lane >> 4;
    const int li   = lane & 15;

    const int rowB = blockIdx.x * 4 * R;           // block's first row
    const int row0 = rowB + grp * R;               // group's first row

    const float4* __restrict__ B4 = reinterpret_cast<const float4*>(Bv);
    const float4* __restrict__ W0 = reinterpret_cast<const float4*>(W) + (size_t)row0 * 512;

    float acc[R][9];
    #pragma unroll
    for (int r = 0; r < R; ++r)
        #pragma unroll
        for (int m = 0; m < 9; ++m) acc[r][m] = 0.0f;

    const int kb4 = w * 128;

    #pragma unroll 4
    for (int it = 0; it < 8; ++it) {
        const int idx = kb4 + it * 16 + li;
        float4 bv[9];
        #pragma unroll
        for (int m = 0; m < 9; ++m) bv[m] = B4[m * 512 + idx];
        #pragma unroll
        for (int r = 0; r < R; ++r) {
            float4 wv = W0[(size_t)r * 512 + idx];
            #pragma unroll
            for (int m = 0; m < 9; ++m) {
                acc[r][m] = fmaf(wv.x, bv[m].x, acc[r][m]);
                acc[r][m] = fmaf(wv.y, bv[m].y, acc[r][m]);
                acc[r][m] = fmaf(wv.z, bv[m].z, acc[r][m]);
                acc[r][m] = fmaf(wv.w, bv[m].w, acc[r][m]);
            }
        }
    }

    #pragma unroll
    for (int r = 0; r < R; ++r)
        #pragma unroll
        for (int m = 0; m < 9; ++m) {
            float v = acc[r][m];
            v += __shfl_xor(v, 1);
            v += __shfl_xor(v, 2);
            v += __shfl_xor(v, 4);
            v += __shfl_xor(v, 8);
            acc[r][m] = v;
        }

    if (li == 0) {
        #pragma unroll
        for (int r = 0; r < R; ++r)
            #pragma unroll
            for (int m = 0; m < 9; ++m)
                lds[w][grp * R + r][m] = acc[r][m];
    }
    __syncthreads();

    for (int t = tid; t < 4 * R * 9; t += 256) {
        const int row = t / 9;
        const int m   = t - row * 9;
        float v = lds[0][row][m] + lds[1][row][m] + lds[2][row][m] + lds[3][row][m];
        const int grow = rowB + row;
        Out[(size_t)m * nrows + grow] = v + bias[grow];
    }
}

// ---------------------------------------------------------------------------
// Kernel 4: per sample a: t[s] = sum_{k=0..8} Z[a*18432 + s*9 + k];
//           instance_norm over s; softmax over s.  (Z includes lin bias.)
// ---------------------------------------------------------------------------
__device__ __forceinline__ float block_reduce(float v, float* red, int tid, int op) {
    #pragma unroll
    for (int off = 32; off > 0; off >>= 1) {
        float o = __shfl_xor(v, off);
        v = op ? fmaxf(v, o) : (v + o);
    }
    __syncthreads();
    if ((tid & 63) == 0) red[tid >> 6] = v;
    __syncthreads();
    float r = red[0];
    #pragma unroll
    for (int w = 1; w < 8; ++w) r = op ? fmaxf(r, red[w]) : (r + red[w]);
    return r;
}

__global__ void k_final(const float* __restrict__ Z,  // [92160] flat
                        float* __restrict__ out)      // [5][2048]
{
    __shared__ float t[2048];
    __shared__ float red[8];
    const int a = blockIdx.x;
    const int tid = threadIdx.x;  // 512 threads

    for (int s = tid; s < 2048; s += 512) {
        const float* zp = Z + a * 18432 + s * 9;
        float acc = 0.0f;
        #pragma unroll
        for (int k = 0; k < 9; ++k) acc += zp[k];
        t[s] = acc;
    }
    __syncthreads();

    float l0 = t[tid], l1 = t[tid + 512], l2 = t[tid + 1024], l3 = t[tid + 1536];

    float ssum = block_reduce(l0 + l1 + l2 + l3, red, tid, 0);
    float mean = ssum * (1.0f / 2048.0f);
    float e0 = l0 - mean, e1 = l1 - mean, e2 = l2 - mean, e3 = l3 - mean;
    float vsum = block_reduce(e0 * e0 + e1 * e1 + e2 * e2 + e3 * e3, red, tid, 0);
    float rstd = 1.0f / sqrtf(vsum * (1.0f / 2048.0f) + 1e-9f);
    float xn0 = e0 * rstd, xn1 = e1 * rstd, xn2 = e2 * rstd, xn3 = e3 * rstd;

    float mx = block_reduce(fmaxf(fmaxf(xn0, xn1), fmaxf(xn2, xn3)), red, tid, 1);
    float ex0 = expf(xn0 - mx), ex1 = expf(xn1 - mx), ex2 = expf(xn2 - mx), ex3 = expf(xn3 - mx);
    float esum = block_reduce(ex0 + ex1 + ex2 + ex3, red, tid, 0);
    float inv = 1.0f / esum;

    out[a * 2048 + tid]        = ex0 * inv;
    out[a * 2048 + tid + 512]  = ex1 * inv;
    out[a * 2048 + tid + 1024] = ex2 * inv;
    out[a * 2048 + tid + 1536] = ex3 * inv;
}

// ---------------------------------------------------------------------------
extern "C" void kernel_launch(void* const* d_in, const int* in_sizes, int n_in,
                              void* d_out, int out_size, void* d_ws, size_t ws_size,
                              hipStream_t stream)
{
    const float* signal = (const float*)d_in[0];
    const float* u1     = (const float*)d_in[1];
    const float* u2     = (const float*)d_in[2];
    const float* bilW   = (const float*)d_in[3];
    const float* bilb   = (const float*)d_in[4];
    const float* Wih1   = (const float*)d_in[5];
    // d_in[6] = Whh1 : unused (h0 = 0)
    const float* bih1   = (const float*)d_in[7];
    const float* bhh1   = (const float*)d_in[8];
    const float* Wih2   = (const float*)d_in[9];
    // d_in[10] = Whh2 : unused
    const float* bih2   = (const float*)d_in[11];
    const float* bhh2   = (const float*)d_in[12];
    const float* linW   = (const float*)d_in[13];
    const float* linb   = (const float*)d_in[14];

    float* out = (float*)d_out;
    float* ws  = (float*)d_ws;

    // workspace layout (floats): B1[18432] B2[18432] Z[92160]  (~516 KB)
    float* B1 = ws;
    float* B2 = ws + 18432;
    float* B3 = B1;             // reuse (B1 dead after LSTM 1)
    float* Z  = ws + 36864;

    k_pre<<<8, 256, 0, stream>>>(signal, u1, bilW, bilb, B1);

    // LSTM layers: gemv + nonlinearity fused, grid 512 = exactly 2 blocks/CU
    k_lstm_fused<true><<<512, 256, 0, stream>>>(B1, Wih1, bih1, bhh1, u2, B2);
    k_lstm_fused<false><<<512, 256, 0, stream>>>(B2, Wih2, bih2, bhh2, nullptr, B3);

    // Linear: 10240 rows, 20 rows/block -> 512 blocks = 2/CU
    k_gemvR<5><<<512, 256, 0, stream>>>(B3, linW, linb, Z, 10240);

    // reshape-sum over 9, instance norm + softmax over 2048
    k_final<<<5, 512, 0, stream>>>(Z, out);
}

// Round 8
// 58.063 us; speedup vs baseline: 1.1757x; 1.1757x over previous
//
#include <hip/hip_runtime.h>
#include <math.h>

#define IOTA_F (1.0f / 137.0f)
#define PHI_F  0.618033988749894f

__device__ __forceinline__ float sigm(float x) { return 1.0f / (1.0f + expf(-x)); }

__device__ __forceinline__ float nan2num(float v) {
    if (isnan(v)) return IOTA_F;
    if (isinf(v)) return v > 0.0f ? 1.0f : IOTA_F;
    return v;
}

// ---------------------------------------------------------------------------
// Kernel 1: instance_norm(5) -> rfft(5) -> re*im -> sigmoid -> softmax(3)
//           -> bilinear(3x3 -> 9) -> mask(u1) -> B1[9][2048]
// ---------------------------------------------------------------------------
__global__ void k_pre(const float* __restrict__ signal,  // [5][2048]
                      const float* __restrict__ u1,      // [9][2048]
                      const float* __restrict__ bilW,    // [9][3][3]
                      const float* __restrict__ bilb,    // [9]
                      float* __restrict__ B1)            // [9][2048]
{
    int s = blockIdx.x * blockDim.x + threadIdx.x;
    if (s >= 2048) return;

    float x0 = signal[0 * 2048 + s];
    float x1 = signal[1 * 2048 + s];
    float x2 = signal[2 * 2048 + s];
    float x3 = signal[3 * 2048 + s];
    float x4 = signal[4 * 2048 + s];

    float mean = (x0 + x1 + x2 + x3 + x4) * 0.2f;
    float d0 = x0 - mean, d1 = x1 - mean, d2 = x2 - mean, d3 = x3 - mean, d4 = x4 - mean;
    float var = (d0 * d0 + d1 * d1 + d2 * d2 + d3 * d3 + d4 * d4) * 0.2f;
    float r = 1.0f / sqrtf(var + 1e-9f);
    d0 *= r; d1 *= r; d2 *= r; d3 *= r; d4 *= r;

    const float c1 = 0.30901699437494742f;   // cos(2pi/5)
    const float c2 = -0.80901699437494745f;  // cos(4pi/5)
    const float s1 = 0.95105651629515357f;   // sin(2pi/5)
    const float s2 = 0.58778525229247314f;   // sin(4pi/5)

    float re1 = d0 + c1 * (d1 + d4) + c2 * (d2 + d3);
    float im1 = -(s1 * (d1 - d4) + s2 * (d2 - d3));
    float re2 = d0 + c2 * (d1 + d4) + c1 * (d2 + d3);
    float im2 = -s2 * (d1 - d4) + s1 * (d2 - d3);

    float p1 = nan2num(re1 * im1);
    float p2 = nan2num(re2 * im2);
    float g0 = 0.5f;                 // k=0: imag == 0 -> sigmoid(0) = 0.5
    float g1 = sigm(p1);
    float g2 = sigm(p2);

    float mx = fmaxf(g0, fmaxf(g1, g2));
    float e0 = expf(g0 - mx), e1 = expf(g1 - mx), e2 = expf(g2 - mx);
    float inv = 1.0f / (e0 + e1 + e2);
    float w[3] = { e0 * inv, e1 * inv, e2 * inv };

    #pragma unroll
    for (int kk = 0; kk < 9; ++kk) {
        float acc = bilb[kk];
        #pragma unroll
        for (int i = 0; i < 3; ++i)
            #pragma unroll
            for (int j = 0; j < 3; ++j)
                acc += w[i] * bilW[kk * 9 + i * 3 + j] * w[j];
        float mask = (u1[kk * 2048 + s] < PHI_F) ? 1.0f : 0.0f;
        B1[kk * 2048 + s] = IOTA_F + acc * mask;
    }
}

// ---------------------------------------------------------------------------
// Kernel 2: fused LSTM layer (gemv + nonlinearity) — round-4 structure with
// B staged in LDS (72 KB). Block = 4 waves, 4 q-columns (grid 512 = 2/CU).
//   Staging: all 256 threads copy B[9][2048] -> LDS (18 float4 each).
//   wave w owns K-chunk w (512 floats); group g (16 lanes) owns q = q0+g and
//   its 3 live gate rows {q, 4096+q, 6144+q} (f dead: c0 = 0).
//   Inner loop: 3 HBM W-loads + 9 LDS B-reads per iter -> VMEM queue holds
//   only HBM-latency loads, pipelined across iters.
// ---------------------------------------------------------------------------
template <bool MASK>
__global__ __launch_bounds__(256, 2) void k_lstm_fused(
    const float* __restrict__ Bv,   // [9][2048]
    const float* __restrict__ W,    // [8192][2048]
    const float* __restrict__ b1,   // [8192]
    const float* __restrict__ b2,   // [8192]
    const float* __restrict__ u,    // [9][2048] or null
    float* __restrict__ Bout)       // [9][2048]
{
    __shared__ float4 Bs[9 * 512];          // 72 KB staged B
    __shared__ float lds[4][4][3][9];       // cross-wave reduce

    const int tid  = threadIdx.x;
    const int w    = tid >> 6;      // wave = K-chunk
    const int lane = tid & 63;
    const int grp  = lane >> 4;     // q within block
    const int li   = lane & 15;

    // stage B -> LDS (coalesced, 18 float4 per thread)
    {
        const float4* __restrict__ Bg = reinterpret_cast<const float4*>(Bv);
        #pragma unroll
        for (int k = 0; k < 18; ++k)
            Bs[tid + k * 256] = Bg[tid + k * 256];
    }
    __syncthreads();

    const int q = blockIdx.x * 4 + grp;

    const float4* __restrict__ Wi = reinterpret_cast<const float4*>(W) + (size_t)q * 512;
    const float4* __restrict__ Wg = Wi + (size_t)4096 * 512;
    const float4* __restrict__ Wo = Wi + (size_t)6144 * 512;

    float acc[3][9];
    #pragma unroll
    for (int r = 0; r < 3; ++r)
        #pragma unroll
        for (int m = 0; m < 9; ++m) acc[r][m] = 0.0f;

    const int kb4 = w * 128;

    #pragma unroll 2
    for (int it = 0; it < 8; ++it) {
        const int idx = kb4 + it * 16 + li;
        float4 wv0 = Wi[idx];
        float4 wv1 = Wg[idx];
        float4 wv2 = Wo[idx];
        #pragma unroll
        for (int m = 0; m < 9; ++m) {
            float4 bv = Bs[m * 512 + idx];
            acc[0][m] = fmaf(wv0.x, bv.x, acc[0][m]);
            acc[0][m] = fmaf(wv0.y, bv.y, acc[0][m]);
            acc[0][m] = fmaf(wv0.z, bv.z, acc[0][m]);
            acc[0][m] = fmaf(wv0.w, bv.w, acc[0][m]);
            acc[1][m] = fmaf(wv1.x, bv.x, acc[1][m]);
            acc[1][m] = fmaf(wv1.y, bv.y, acc[1][m]);
            acc[1][m] = fmaf(wv1.z, bv.z, acc[1][m]);
            acc[1][m] = fmaf(wv1.w, bv.w, acc[1][m]);
            acc[2][m] = fmaf(wv2.x, bv.x, acc[2][m]);
            acc[2][m] = fmaf(wv2.y, bv.y, acc[2][m]);
            acc[2][m] = fmaf(wv2.z, bv.z, acc[2][m]);
            acc[2][m] = fmaf(wv2.w, bv.w, acc[2][m]);
        }
    }

    #pragma unroll
    for (int r = 0; r < 3; ++r)
        #pragma unroll
        for (int m = 0; m < 9; ++m) {
            float v = acc[r][m];
            v += __shfl_xor(v, 1);
            v += __shfl_xor(v, 2);
            v += __shfl_xor(v, 4);
            v += __shfl_xor(v, 8);
            acc[r][m] = v;
        }

    if (li == 0) {
        #pragma unroll
        for (int r = 0; r < 3; ++r)
            #pragma unroll
            for (int m = 0; m < 9; ++m)
                lds[w][grp][r][m] = acc[r][m];
    }
    __syncthreads();

    if (tid < 36) {
        const int qq = tid / 9;
        const int m  = tid - qq * 9;
        const int qg = blockIdx.x * 4 + qq;
        float iv = lds[0][qq][0][m] + lds[1][qq][0][m] + lds[2][qq][0][m] + lds[3][qq][0][m];
        float gv = lds[0][qq][1][m] + lds[1][qq][1][m] + lds[2][qq][1][m] + lds[3][qq][1][m];
        float ov = lds[0][qq][2][m] + lds[1][qq][2][m] + lds[2][qq][2][m] + lds[3][qq][2][m];
        iv += b1[qg] + b2[qg];
        gv += b1[4096 + qg] + b2[4096 + qg];
        ov += b1[6144 + qg] + b2[6144 + qg];
        float c = sigm(iv) * tanhf(gv);
        float h = sigm(ov) * tanhf(c);
        if (MASK) h = IOTA_F + h * ((u[m * 2048 + qg] < PHI_F) ? 1.0f : 0.0f);
        Bout[m * 2048 + qg] = h;
    }
}

// ---------------------------------------------------------------------------
// Kernel 3: linear gemv — round-4 structure with B staged in LDS.
// Block = 4 waves, 20 rows (grid 512 = 2/CU, R=5).
// ---------------------------------------------------------------------------
template <int R>
__global__ __launch_bounds__(256, 2) void k_gemvR(
    const float* __restrict__ Bv,    // [9][2048]
    const float* __restrict__ W,     // [nrows][2048]
    const float* __restrict__ bias,  // [nrows]
    float* __restrict__ Out,         // [9][nrows]
    int nrows)
{
    __shared__ float4 Bs[9 * 512];          // 72 KB staged B
    __shared__ float lds[4][4 * R][9];

    const int tid  = threadIdx.x;
    const int w    = tid >> 6;
    const int lane = tid & 63;
    const int grp  = lane >> 4;
    const int li   = lane & 15;

    {
        const float4* __restrict__ Bg = reinterpret_cast<const float4*>(Bv);
        #pragma unroll
        for (int k = 0; k < 18; ++k)
            Bs[tid + k * 256] = Bg[tid + k * 256];
    }
    __syncthreads();

    const int rowB = blockIdx.x * 4 * R;           // block's first row
    const int row0 = rowB + grp * R;               // group's first row

    const float4* __restrict__ W0 = reinterpret_cast<const float4*>(W) + (size_t)row0 * 512;

    float acc[R][9];
    #pragma unroll
    for (int r = 0; r < R; ++r)
        #pragma unroll
        for (int m = 0; m < 9; ++m) acc[r][m] = 0.0f;

    const int kb4 = w * 128;

    #pragma unroll 2
    for (int it = 0; it < 8; ++it) {
        const int idx = kb4 + it * 16 + li;
        float4 wv[R];
        #pragma unroll
        for (int r = 0; r < R; ++r) wv[r] = W0[(size_t)r * 512 + idx];
        #pragma unroll
        for (int m = 0; m < 9; ++m) {
            float4 bv = Bs[m * 512 + idx];
            #pragma unroll
            for (int r = 0; r < R; ++r) {
                acc[r][m] = fmaf(wv[r].x, bv.x, acc[r][m]);
                acc[r][m] = fmaf(wv[r].y, bv.y, acc[r][m]);
                acc[r][m] = fmaf(wv[r].z, bv.z, acc[r][m]);
                acc[r][m] = fmaf(wv[r].w, bv.w, acc[r][m]);
            }
        }
    }

    #pragma unroll
    for (int r = 0; r < R; ++r)
        #pragma unroll
        for (int m = 0; m < 9; ++m) {
            float v = acc[r][m];
            v += __shfl_xor(v, 1);
            v += __shfl_xor(v, 2);
            v += __shfl_xor(v, 4);
            v += __shfl_xor(v, 8);
            acc[r][m] = v;
        }

    if (li == 0) {
        #pragma unroll
        for (int r = 0; r < R; ++r)
            #pragma unroll
            for (int m = 0; m < 9; ++m)
                lds[w][grp * R + r][m] = acc[r][m];
    }
    __syncthreads();

    for (int t = tid; t < 4 * R * 9; t += 256) {
        const int row = t / 9;
        const int m   = t - row * 9;
        float v = lds[0][row][m] + lds[1][row][m] + lds[2][row][m] + lds[3][row][m];
        const int grow = rowB + row;
        Out[(size_t)m * nrows + grow] = v + bias[grow];
    }
}

// ---------------------------------------------------------------------------
// Kernel 4: per sample a: t[s] = sum_{k=0..8} Z[a*18432 + s*9 + k];
//           instance_norm over s; softmax over s.  (Z includes lin bias.)
// ---------------------------------------------------------------------------
__device__ __forceinline__ float block_reduce(float v, float* red, int tid, int op) {
    #pragma unroll
    for (int off = 32; off > 0; off >>= 1) {
        float o = __shfl_xor(v, off);
        v = op ? fmaxf(v, o) : (v + o);
    }
    __syncthreads();
    if ((tid & 63) == 0) red[tid >> 6] = v;
    __syncthreads();
    float r = red[0];
    #pragma unroll
    for (int w = 1; w < 8; ++w) r = op ? fmaxf(r, red[w]) : (r + red[w]);
    return r;
}

__global__ void k_final(const float* __restrict__ Z,  // [92160] flat
                        float* __restrict__ out)      // [5][2048]
{
    __shared__ float t[2048];
    __shared__ float red[8];
    const int a = blockIdx.x;
    const int tid = threadIdx.x;  // 512 threads

    for (int s = tid; s < 2048; s += 512) {
        const float* zp = Z + a * 18432 + s * 9;
        float acc = 0.0f;
        #pragma unroll
        for (int k = 0; k < 9; ++k) acc += zp[k];
        t[s] = acc;
    }
    __syncthreads();

    float l0 = t[tid], l1 = t[tid + 512], l2 = t[tid + 1024], l3 = t[tid + 1536];

    float ssum = block_reduce(l0 + l1 + l2 + l3, red, tid, 0);
    float mean = ssum * (1.0f / 2048.0f);
    float e0 = l0 - mean, e1 = l1 - mean, e2 = l2 - mean, e3 = l3 - mean;
    float vsum = block_reduce(e0 * e0 + e1 * e1 + e2 * e2 + e3 * e3, red, tid, 0);
    float rstd = 1.0f / sqrtf(vsum * (1.0f / 2048.0f) + 1e-9f);
    float xn0 = e0 * rstd, xn1 = e1 * rstd, xn2 = e2 * rstd, xn3 = e3 * rstd;

    float mx = block_reduce(fmaxf(fmaxf(xn0, xn1), fmaxf(xn2, xn3)), red, tid, 1);
    float ex0 = expf(xn0 - mx), ex1 = expf(xn1 - mx), ex2 = expf(xn2 - mx), ex3 = expf(xn3 - mx);
    float esum = block_reduce(ex0 + ex1 + ex2 + ex3, red, tid, 0);
    float inv = 1.0f / esum;

    out[a * 2048 + tid]        = ex0 * inv;
    out[a * 2048 + tid + 512]  = ex1 * inv;
    out[a * 2048 + tid + 1024] = ex2 * inv;
    out[a * 2048 + tid + 1536] = ex3 * inv;
}

// ---------------------------------------------------------------------------
extern "C" void kernel_launch(void* const* d_in, const int* in_sizes, int n_in,
                              void* d_out, int out_size, void* d_ws, size_t ws_size,
                              hipStream_t stream)
{
    const float* signal = (const float*)d_in[0];
    const float* u1     = (const float*)d_in[1];
    const float* u2     = (const float*)d_in[2];
    const float* bilW   = (const float*)d_in[3];
    const float* bilb   = (const float*)d_in[4];
    const float* Wih1   = (const float*)d_in[5];
    // d_in[6] = Whh1 : unused (h0 = 0)
    const float* bih1   = (const float*)d_in[7];
    const float* bhh1   = (const float*)d_in[8];
    const float* Wih2   = (const float*)d_in[9];
    // d_in[10] = Whh2 : unused
    const float* bih2   = (const float*)d_in[11];
    const float* bhh2   = (const float*)d_in[12];
    const float* linW   = (const float*)d_in[13];
    const float* linb   = (const float*)d_in[14];

    float* out = (float*)d_out;
    float* ws  = (float*)d_ws;

    // workspace layout (floats): B1[18432] B2[18432] Z[92160]  (~516 KB)
    float* B1 = ws;
    float* B2 = ws + 18432;
    float* B3 = B1;             // reuse (B1 dead after LSTM 1)
    float* Z  = ws + 36864;

    k_pre<<<8, 256, 0, stream>>>(signal, u1, bilW, bilb, B1);

    // LSTM layers: gemv + nonlinearity fused, grid 512 = exactly 2 blocks/CU
    k_lstm_fused<true><<<512, 256, 0, stream>>>(B1, Wih1, bih1, bhh1, u2, B2);
    k_lstm_fused<false><<<512, 256, 0, stream>>>(B2, Wih2, bih2, bhh2, nullptr, B3);

    // Linear: 10240 rows, 20 rows/block -> 512 blocks = 2/CU
    k_gemvR<5><<<512, 256, 0, stream>>>(B3, linW, linb, Z, 10240);

    // reshape-sum over 9, instance norm + softmax over 2048
    k_final<<<5, 512, 0, stream>>>(Z, out);
}